// Round 1
// baseline (489.109 us; speedup 1.0000x reference)
//
#include <hip/hip_runtime.h>
#include <hip/hip_bf16.h>

typedef unsigned short u16;
typedef unsigned int u32;
typedef unsigned long long u64;
typedef __attribute__((ext_vector_type(8))) short short8;
typedef __attribute__((ext_vector_type(4))) float f32x4;

#define NN 8192
#define KIN 256
#define FOUT 128
#define SPLITS 8
#define KPER (NN / SPLITS)   // 1024
#define KSTEPS (KPER / 32)   // 32 k-steps of 32 per split
#define NWORDS (NN / 32)     // 256 bitmask words per row
#define L2E 1.4426950408889634f

__device__ __forceinline__ float exp2fast(float x) { return __builtin_amdgcn_exp2f(x); }

__device__ __forceinline__ u16 f2bf(float f) {
    u32 u = __float_as_uint(f);
    u32 r = ((u >> 16) & 1u) + 0x7fffu;
    return (u16)((u + r) >> 16);
}
__device__ __forceinline__ u32 pk_bf16(float a, float b) {
    union { __hip_bfloat162 h2; u32 u; } cv;
    cv.h2 = __float22bfloat162_rn(make_float2(a, b));   // v_cvt_pk_bf16_f32
    return cv.u;
}
__device__ __forceinline__ u32 fkey(float f) {
    u32 b = __float_as_uint(f);
    return (b & 0x80000000u) ? ~b : (b | 0x80000000u);
}
__device__ __forceinline__ float funkey(u32 k) {
    u32 b = (k & 0x80000000u) ? (k & 0x7fffffffu) : ~k;
    return __uint_as_float(b);
}

// ---------------- K0: pack adj (268 MB int32) -> bitmask (8.4 MB), pure stream ----
// wave reads 64 consecutive ints (256 B coalesced), ballot -> one u64 word.
__global__ __launch_bounds__(256) void k0_pack(const int* __restrict__ adj,
                                               u64* __restrict__ bm)
{
    const int lane = threadIdx.x & 63;
    const u32 wid = (blockIdx.x * 256 + threadIdx.x) >> 6;
    const u32 nw  = (gridDim.x * 256) >> 6;
    const u32 total = (u32)(((size_t)NN * NN) >> 6);   // 1048576 chunks
    for (u32 c = wid; c < total; c += nw) {
        int v = adj[(size_t)c * 64 + lane];
        u64 b = __ballot(v > 0);
        if (lane == 0) bm[c] = b;
    }
}

// ---------------- K1: Wh = h@W (fp32 acc) -> whfrag (B-fragment-major bf16), src, dst*log2e, gmax
// whfrag layout: [(kstep*8 + ntile)*64 + lane] * 8 u16, element j = Wh[kstep*32 + (lane>>4)*8 + j][ntile*16 + (lane&15)]
__global__ __launch_bounds__(256) void k1_wh(
    const float* __restrict__ h, const float* __restrict__ W, const float* __restrict__ a,
    u16* __restrict__ whfrag,
    float* __restrict__ src, float* __restrict__ dl2e, u32* __restrict__ gmaxk)
{
    __shared__ float hT[64][36];
    __shared__ u16   lt[128][40];    // [feature][node] bf16 tile, 80B row stride
    __shared__ float sd[32][2];
    const int t  = threadIdx.x;
    const int m0 = blockIdx.x * 32;  // node block; kstep = blockIdx.x
    const int rq = t >> 5, cq = t & 31;

    float acc[4][4];
#pragma unroll
    for (int i = 0; i < 4; i++)
#pragma unroll
        for (int j = 0; j < 4; j++) acc[i][j] = 0.f;
    if (t < 64) sd[t >> 1][t & 1] = 0.f;

    for (int kt = 0; kt < KIN; kt += 64) {
        __syncthreads();
#pragma unroll
        for (int s2 = 0; s2 < 2; s2++) {
            int f = s2 * 256 + t;
            int r = f >> 4, kc = (f & 15) * 4;
            float4 hv = *(const float4*)(h + (size_t)(m0 + r) * KIN + kt + kc);
            hT[kc + 0][r] = hv.x; hT[kc + 1][r] = hv.y;
            hT[kc + 2][r] = hv.z; hT[kc + 3][r] = hv.w;
        }
        __syncthreads();
        for (int k = 0; k < 64; k++) {
            float4 wv = *(const float4*)(W + (size_t)(kt + k) * FOUT + cq * 4);
            float h0 = hT[k][rq * 4 + 0], h1 = hT[k][rq * 4 + 1];
            float h2 = hT[k][rq * 4 + 2], h3 = hT[k][rq * 4 + 3];
            acc[0][0] += h0 * wv.x; acc[0][1] += h0 * wv.y; acc[0][2] += h0 * wv.z; acc[0][3] += h0 * wv.w;
            acc[1][0] += h1 * wv.x; acc[1][1] += h1 * wv.y; acc[1][2] += h1 * wv.z; acc[1][3] += h1 * wv.w;
            acc[2][0] += h2 * wv.x; acc[2][1] += h2 * wv.y; acc[2][2] += h2 * wv.z; acc[2][3] += h2 * wv.w;
            acc[3][0] += h3 * wv.x; acc[3][1] += h3 * wv.y; acc[3][2] += h3 * wv.z; acc[3][3] += h3 * wv.w;
        }
    }
#pragma unroll
    for (int i = 0; i < 4; i++) {
        float sp = 0.f, dp = 0.f;
#pragma unroll
        for (int j = 0; j < 4; j++) {
            sp += acc[i][j] * a[cq * 4 + j];
            dp += acc[i][j] * a[FOUT + cq * 4 + j];
            lt[cq * 4 + j][rq * 4 + i] = f2bf(acc[i][j]);
        }
        atomicAdd(&sd[rq * 4 + i][0], sp);
        atomicAdd(&sd[rq * 4 + i][1], dp);
    }
    __syncthreads();
    if (t < 32) { src[m0 + t] = sd[t][0]; dl2e[m0 + t] = sd[t][1] * L2E; }
    if (t < 64) {
        float v = (t < 32) ? sd[t][1] : -3.0e38f;
#pragma unroll
        for (int off = 32; off >= 1; off >>= 1) v = fmaxf(v, __shfl_down(v, off));
        if (t == 0) atomicMax(gmaxk, fkey(v));
    }
    // fragment-major write: 8 ntiles x 64 lanes x 16B, fully coalesced
    const int kstep = blockIdx.x;
#pragma unroll
    for (int p = 0; p < 2; p++) {
        int f = p * 256 + t;         // 0..511
        int nt = f >> 6;             // 0..7
        int l  = f & 63;
        short8 v = *(const short8*)&lt[nt * 16 + (l & 15)][(l >> 4) * 8];
        *(short8*)(whfrag + ((size_t)(kstep * 8 + nt) * 64 + l) * 8) = v;
    }
}

// ---------------- K2: barrier-free flash attention; wave = 16-row strip, no LDS -----
// adj is consumed as a bitmask: one broadcast u32 per lane per k-step (L1-resident:
// a row's whole per-split bit range is exactly one 128B line).
__global__ __launch_bounds__(256, 4) void k2_attn(
    const u32* __restrict__ bmask, const float* __restrict__ src, const float* __restrict__ dl2e,
    const u16* __restrict__ whfrag, const u32* __restrict__ gmaxk,
    float* __restrict__ accp, float* __restrict__ lp)
{
    const int t = threadIdx.x;
    const int lane = t & 63, wave = t >> 6;
    const int strip = blockIdx.x * 4 + wave;     // 0..511 (16-row m-tile)
    const int i0 = strip * 16;
    const int split = blockIdx.y;
    const int l15 = lane & 15;
    const int kq = (lane >> 4) * 8;              // this lane's k offset within a 32-step

    float sp = src[i0 + l15] * L2E;
    float gm = funkey(*gmaxk) * L2E;
    float xx = sp + gm;
    float C = fmaxf(xx, 0.01f * xx);
    const float y1 = sp - C, y2 = 0.01f * sp - C;

    const u32* brow = bmask + (size_t)(i0 + l15) * NWORDS;   // lane's bit-row
    const int st0 = blockIdx.x & (KSTEPS - 1);               // stagger windows across blocks
    const int kbase = split * KPER;

    f32x4 acc[8];
#pragma unroll
    for (int nt = 0; nt < 8; nt++) acc[nt] = {0.f, 0.f, 0.f, 0.f};
    float psum = 0.f;

#pragma unroll 4
    for (int it = 0; it < KSTEPS; ++it) {
        const int kb = kbase + ((st0 + it) & (KSTEPS - 1)) * 32;

        // B fragments: contiguous 1KB/wave per tile, L1/L2-resident
        uint4 bv[8];
        const u16* wf = whfrag + ((size_t)(kb >> 5) * 8 * 64 + lane) * 8;
#pragma unroll
        for (int nt = 0; nt < 8; nt++)
            bv[nt] = *(const uint4*)(wf + (size_t)nt * 64 * 8);

        // mask bits + dst values (both broadcast loads, L1-resident)
        const u32 ab = brow[kb >> 5] >> kq;
        const float4 dl = *(const float4*)(dl2e + kb + kq);
        const float4 dh = *(const float4*)(dl2e + kb + kq + 4);

        // P in A-fragment layout (row = l15, k = kq + j), lane-private
        float p0, p1, p2, p3, p4, p5, p6, p7;
        {
            float x;
            x = fmaxf(y1 + dl.x, y2 + 0.01f * dl.x); p0 = exp2fast((ab &   1u) ? x : -1.0e9f);
            x = fmaxf(y1 + dl.y, y2 + 0.01f * dl.y); p1 = exp2fast((ab &   2u) ? x : -1.0e9f);
            x = fmaxf(y1 + dl.z, y2 + 0.01f * dl.z); p2 = exp2fast((ab &   4u) ? x : -1.0e9f);
            x = fmaxf(y1 + dl.w, y2 + 0.01f * dl.w); p3 = exp2fast((ab &   8u) ? x : -1.0e9f);
            x = fmaxf(y1 + dh.x, y2 + 0.01f * dh.x); p4 = exp2fast((ab &  16u) ? x : -1.0e9f);
            x = fmaxf(y1 + dh.y, y2 + 0.01f * dh.y); p5 = exp2fast((ab &  32u) ? x : -1.0e9f);
            x = fmaxf(y1 + dh.z, y2 + 0.01f * dh.z); p6 = exp2fast((ab &  64u) ? x : -1.0e9f);
            x = fmaxf(y1 + dh.w, y2 + 0.01f * dh.w); p7 = exp2fast((ab & 128u) ? x : -1.0e9f);
        }
        psum += ((p0 + p1) + (p2 + p3)) + ((p4 + p5) + (p6 + p7));
        union { short8 s8; u32 u[4]; } af;
        af.u[0] = pk_bf16(p0, p1); af.u[1] = pk_bf16(p2, p3);
        af.u[2] = pk_bf16(p4, p5); af.u[3] = pk_bf16(p6, p7);

#pragma unroll
        for (int nt = 0; nt < 8; nt++) {
            union { uint4 q; short8 s8; } bf; bf.q = bv[nt];
            acc[nt] = __builtin_amdgcn_mfma_f32_16x16x32_bf16(af.s8, bf.s8, acc[nt], 0, 0, 0);
        }
    }

    // row sums: reduce over the 4 quads holding each row
    float v = psum;
    v += __shfl_down(v, 32);
    v += __shfl_down(v, 16);
    if (lane < 16) lp[split * NN + i0 + lane] = v;

    // accumulator partials, lane-major tile layout (fully coalesced)
    float* ab2 = accp + (size_t)split * (NN * FOUT);
#pragma unroll
    for (int nt = 0; nt < 8; nt++)
        *(f32x4*)&ab2[((size_t)(strip * 8 + nt) * 64 + lane) * 4] = acc[nt];
}

// ---------------- K2b: inverse row sums --------------------------------------------
__global__ __launch_bounds__(256) void k2b_rsum(const float* __restrict__ lp,
                                               float* __restrict__ rinv)
{
    int i = blockIdx.x * 256 + threadIdx.x;
    float s = 0.f;
#pragma unroll
    for (int sp = 0; sp < SPLITS; sp++) s += lp[sp * NN + i];
    rinv[i] = 1.0f / s;
}

// ---------------- K3: combine splits from tile layout, normalize, store ------------
__global__ __launch_bounds__(256) void k3_comb(
    const float* __restrict__ accp, const float* __restrict__ rinv, float* __restrict__ out)
{
    int idx = blockIdx.x * 256 + threadIdx.x;   // float4 index over tile storage
    int tile = idx >> 6, l = idx & 63;
    float4 s = make_float4(0.f, 0.f, 0.f, 0.f);
#pragma unroll
    for (int sp = 0; sp < SPLITS; sp++) {
        float4 v = *(const float4*)(accp + (size_t)sp * (NN * FOUT) + (size_t)idx * 4);
        s.x += v.x; s.y += v.y; s.z += v.z; s.w += v.w;
    }
    int row0 = (tile >> 3) * 16 + (l >> 4) * 4;
    int col  = (tile & 7) * 16 + (l & 15);
    float4 ri = *(const float4*)(rinv + row0);
    out[(size_t)(row0 + 0) * FOUT + col] = s.x * ri.x;
    out[(size_t)(row0 + 1) * FOUT + col] = s.y * ri.y;
    out[(size_t)(row0 + 2) * FOUT + col] = s.z * ri.z;
    out[(size_t)(row0 + 3) * FOUT + col] = s.w * ri.w;
}

extern "C" void kernel_launch(void* const* d_in, const int* in_sizes, int n_in,
                              void* d_out, int out_size, void* d_ws, size_t ws_size,
                              hipStream_t stream) {
    const float* h   = (const float*)d_in[0];
    const int*   adj = (const int*)d_in[1];
    const float* W   = (const float*)d_in[2];
    const float* a   = (const float*)d_in[3];
    float* out = (float*)d_out;

    char* ws = (char*)d_ws;
    u16*   whfrag = (u16*)ws;                           // 2 MB
    float* src    = (float*)(ws + (2u << 20));          // 32 KB
    float* dl2e   = src + NN;                           // 32 KB
    u32*   gmaxk  = (u32*)(dl2e + NN);                  // 4 B
    float* accp   = (float*)(ws + (3u << 20));          // 32 MB
    float* lp     = (float*)(ws + (35u << 20));         // 256 KB
    float* rinv   = (float*)(ws + (36u << 20));         // 32 KB
    u64*   bmask  = (u64*)(ws + (37u << 20));           // 8 MB

    (void)hipMemsetAsync(gmaxk, 0, sizeof(u32), stream);
    k0_pack<<<dim3(2048), dim3(256), 0, stream>>>(adj, bmask);
    k1_wh<<<dim3(NN / 32), dim3(256), 0, stream>>>(h, W, a, whfrag, src, dl2e, gmaxk);
    k2_attn<<<dim3(NN / 64, SPLITS), dim3(256), 0, stream>>>((const u32*)bmask, src, dl2e, whfrag, gmaxk, accp, lp);
    k2b_rsum<<<dim3(NN / 256), dim3(256), 0, stream>>>(lp, rinv);
    k3_comb<<<dim3((NN * FOUT / 4) / 256), dim3(256), 0, stream>>>(accp, rinv, out);
}

// Round 2
// 433.232 us; speedup vs baseline: 1.1290x; 1.1290x over previous
//
#include <hip/hip_runtime.h>
#include <hip/hip_bf16.h>

typedef unsigned short u16;
typedef unsigned int u32;
typedef __attribute__((ext_vector_type(8))) short short8;
typedef __attribute__((ext_vector_type(4))) float f32x4;

#define NN 8192
#define KIN 256
#define FOUT 128
#define SPLITS 8
#define KPER (NN / SPLITS)   // 1024
#define KSTEPS (KPER / 32)   // 32 k-steps of 32 per split
#define L2E 1.4426950408889634f

__device__ __forceinline__ float exp2fast(float x) { return __builtin_amdgcn_exp2f(x); }

__device__ __forceinline__ u16 f2bf(float f) {
    u32 u = __float_as_uint(f);
    u32 r = ((u >> 16) & 1u) + 0x7fffu;
    return (u16)((u + r) >> 16);
}
__device__ __forceinline__ u32 pk_bf16(float a, float b) {
    union { __hip_bfloat162 h2; u32 u; } cv;
    cv.h2 = __float22bfloat162_rn(make_float2(a, b));   // v_cvt_pk_bf16_f32
    return cv.u;
}
__device__ __forceinline__ u32 fkey(float f) {
    u32 b = __float_as_uint(f);
    return (b & 0x80000000u) ? ~b : (b | 0x80000000u);
}
__device__ __forceinline__ float funkey(u32 k) {
    u32 b = (k & 0x80000000u) ? (k & 0x7fffffffu) : ~k;
    return __uint_as_float(b);
}

// ---------------- K1: Wh = h@W (fp32 acc) -> whfrag (B-fragment-major bf16), src, dst*log2e, gmax
// 512 threads/block (2 waves/SIMD instead of 1 -> W-load latency shared across waves).
// whfrag layout: [(kstep*8 + ntile)*64 + lane] * 8 u16, element j = Wh[kstep*32 + (lane>>4)*8 + j][ntile*16 + (lane&15)]
__global__ __launch_bounds__(512) void k1_wh(
    const float* __restrict__ h, const float* __restrict__ W, const float* __restrict__ a,
    u16* __restrict__ whfrag,
    float* __restrict__ src, float* __restrict__ dl2e, u32* __restrict__ gmaxk)
{
    __shared__ float hT[64][36];
    __shared__ u16   lt[128][40];    // [feature][node] bf16 tile, 80B row stride
    __shared__ float sd[32][2];
    const int t  = threadIdx.x;       // 0..511
    const int m0 = blockIdx.x * 32;   // node block; kstep = blockIdx.x
    const int rq = t >> 5, cq = t & 31;   // rq 0..15, rows rq*2+{0,1}; cols cq*4..+3

    float acc[2][4];
#pragma unroll
    for (int i = 0; i < 2; i++)
#pragma unroll
        for (int j = 0; j < 4; j++) acc[i][j] = 0.f;
    if (t < 64) sd[t >> 1][t & 1] = 0.f;

    for (int kt = 0; kt < KIN; kt += 64) {
        __syncthreads();
        {   // 512 threads stage the full 32x64 h-tile (transposed) in one step
            int r = t >> 4, kc = (t & 15) * 4;
            float4 hv = *(const float4*)(h + (size_t)(m0 + r) * KIN + kt + kc);
            hT[kc + 0][r] = hv.x; hT[kc + 1][r] = hv.y;
            hT[kc + 2][r] = hv.z; hT[kc + 3][r] = hv.w;
        }
        __syncthreads();
        for (int k = 0; k < 64; k++) {
            float4 wv = *(const float4*)(W + (size_t)(kt + k) * FOUT + cq * 4);
            float h0 = hT[k][rq * 2 + 0], h1 = hT[k][rq * 2 + 1];
            acc[0][0] += h0 * wv.x; acc[0][1] += h0 * wv.y; acc[0][2] += h0 * wv.z; acc[0][3] += h0 * wv.w;
            acc[1][0] += h1 * wv.x; acc[1][1] += h1 * wv.y; acc[1][2] += h1 * wv.z; acc[1][3] += h1 * wv.w;
        }
    }
#pragma unroll
    for (int i = 0; i < 2; i++) {
        int row = rq * 2 + i;
        float sp = 0.f, dp = 0.f;
#pragma unroll
        for (int j = 0; j < 4; j++) {
            sp += acc[i][j] * a[cq * 4 + j];
            dp += acc[i][j] * a[FOUT + cq * 4 + j];
            lt[cq * 4 + j][row] = f2bf(acc[i][j]);
        }
        atomicAdd(&sd[row][0], sp);
        atomicAdd(&sd[row][1], dp);
    }
    __syncthreads();
    if (t < 32) { src[m0 + t] = sd[t][0]; dl2e[m0 + t] = sd[t][1] * L2E; }
    if (t < 64) {
        float v = (t < 32) ? sd[t][1] : -3.0e38f;
#pragma unroll
        for (int off = 32; off >= 1; off >>= 1) v = fmaxf(v, __shfl_down(v, off));
        if (t == 0) atomicMax(gmaxk, fkey(v));
    }
    // fragment-major write: 8 ntiles x 64 lanes x 16B, fully coalesced, one step
    const int kstep = blockIdx.x;
    {
        int nt = t >> 6;             // 0..7
        int l  = t & 63;
        short8 v = *(const short8*)&lt[nt * 16 + (l & 15)][(l >> 4) * 8];
        *(short8*)(whfrag + ((size_t)(kstep * 8 + nt) * 64 + l) * 8) = v;
    }
}

// ---------------- K2: barrier-free flash attention; wave = 16-row strip, no LDS -----
// 8 waves/block all share one split and one st0 window -> the 8 KB/iter whfrag
// stream is read once into L1 and reused by all 8 waves (was 4 independent
// windows per CU thrashing the 32 KB L1).
__global__ __launch_bounds__(512, 4) void k2_attn(
    const int* __restrict__ adj, const float* __restrict__ src, const float* __restrict__ dl2e,
    const u16* __restrict__ whfrag, const u32* __restrict__ gmaxk,
    float* __restrict__ accp, float* __restrict__ lp)
{
    const int t = threadIdx.x;
    const int lane = t & 63, wave = t >> 6;
    const int strip = blockIdx.x * 8 + wave;     // 0..511 (16-row m-tile), grid.x = 64
    const int i0 = strip * 16;
    const int split = blockIdx.y;
    const int l15 = lane & 15;
    const int kq = (lane >> 4) * 8;              // this lane's k offset within a 32-step

    float sp = src[i0 + l15] * L2E;
    float gm = funkey(*gmaxk) * L2E;
    float xx = sp + gm;
    float C = fmaxf(xx, 0.01f * xx);
    const float y1 = sp - C, y2 = 0.01f * sp - C;

    const int* arow = adj + (size_t)(i0 + l15) * NN;     // lane's adj row
    const int st0 = blockIdx.x & (KSTEPS - 1);           // stagger windows across blocks
    const int kbase = split * KPER;

    f32x4 acc[8];
#pragma unroll
    for (int nt = 0; nt < 8; nt++) acc[nt] = {0.f, 0.f, 0.f, 0.f};
    float psum = 0.f;

    // depth-2 register prefetch of adj + dst (no barriers anywhere -> loads stay in flight)
    int4 aL[2], aH[2]; float4 dL[2], dH[2];
#pragma unroll
    for (int s = 0; s < 2; s++) {
        int kb = kbase + ((st0 + s) & (KSTEPS - 1)) * 32;
        aL[s] = *(const int4*)(arow + kb + kq);
        aH[s] = *(const int4*)(arow + kb + kq + 4);
        dL[s] = *(const float4*)(dl2e + kb + kq);
        dH[s] = *(const float4*)(dl2e + kb + kq + 4);
    }

#pragma unroll 4
    for (int it = 0; it < KSTEPS; ++it) {
        const int sl = it & 1;
        const int kb = kbase + ((st0 + it) & (KSTEPS - 1)) * 32;

        // B fragments: contiguous 1KB/wave per tile, shared across the block's 8 waves via L1
        uint4 bv[8];
        const u16* wf = whfrag + ((size_t)(kb >> 5) * 8 * 64 + lane) * 8;
#pragma unroll
        for (int nt = 0; nt < 8; nt++)
            bv[nt] = *(const uint4*)(wf + (size_t)nt * 64 * 8);

        // P in A-fragment layout (row = l15, k = kq + j), lane-private
        int4 al = aL[sl], ah = aH[sl];
        float4 dl = dL[sl], dh = dH[sl];
        float p0, p1, p2, p3, p4, p5, p6, p7;
        {
            float x;
            x = fmaxf(y1 + dl.x, y2 + 0.01f * dl.x); p0 = exp2fast(al.x > 0 ? x : -1.0e9f);
            x = fmaxf(y1 + dl.y, y2 + 0.01f * dl.y); p1 = exp2fast(al.y > 0 ? x : -1.0e9f);
            x = fmaxf(y1 + dl.z, y2 + 0.01f * dl.z); p2 = exp2fast(al.z > 0 ? x : -1.0e9f);
            x = fmaxf(y1 + dl.w, y2 + 0.01f * dl.w); p3 = exp2fast(al.w > 0 ? x : -1.0e9f);
            x = fmaxf(y1 + dh.x, y2 + 0.01f * dh.x); p4 = exp2fast(ah.x > 0 ? x : -1.0e9f);
            x = fmaxf(y1 + dh.y, y2 + 0.01f * dh.y); p5 = exp2fast(ah.y > 0 ? x : -1.0e9f);
            x = fmaxf(y1 + dh.z, y2 + 0.01f * dh.z); p6 = exp2fast(ah.z > 0 ? x : -1.0e9f);
            x = fmaxf(y1 + dh.w, y2 + 0.01f * dh.w); p7 = exp2fast(ah.w > 0 ? x : -1.0e9f);
        }
        psum += ((p0 + p1) + (p2 + p3)) + ((p4 + p5) + (p6 + p7));
        union { short8 s8; u32 u[4]; } af;
        af.u[0] = pk_bf16(p0, p1); af.u[1] = pk_bf16(p2, p3);
        af.u[2] = pk_bf16(p4, p5); af.u[3] = pk_bf16(p6, p7);

        // prefetch it+2 into this slot (wrapped index: always valid, branchless)
        {
            int kb2 = kbase + ((st0 + it + 2) & (KSTEPS - 1)) * 32;
            aL[sl] = *(const int4*)(arow + kb2 + kq);
            aH[sl] = *(const int4*)(arow + kb2 + kq + 4);
            dL[sl] = *(const float4*)(dl2e + kb2 + kq);
            dH[sl] = *(const float4*)(dl2e + kb2 + kq + 4);
        }

#pragma unroll
        for (int nt = 0; nt < 8; nt++) {
            union { uint4 q; short8 s8; } bf; bf.q = bv[nt];
            acc[nt] = __builtin_amdgcn_mfma_f32_16x16x32_bf16(af.s8, bf.s8, acc[nt], 0, 0, 0);
        }
    }

    // row sums: reduce over the 4 quads holding each row
    float v = psum;
    v += __shfl_down(v, 32);
    v += __shfl_down(v, 16);
    if (lane < 16) lp[split * NN + i0 + lane] = v;

    // accumulator partials, lane-major tile layout (fully coalesced)
    float* ab2 = accp + (size_t)split * (NN * FOUT);
#pragma unroll
    for (int nt = 0; nt < 8; nt++)
        *(f32x4*)&ab2[((size_t)(strip * 8 + nt) * 64 + lane) * 4] = acc[nt];
}

// ---------------- K2b: inverse row sums --------------------------------------------
__global__ __launch_bounds__(256) void k2b_rsum(const float* __restrict__ lp,
                                               float* __restrict__ rinv)
{
    int i = blockIdx.x * 256 + threadIdx.x;
    float s = 0.f;
#pragma unroll
    for (int sp = 0; sp < SPLITS; sp++) s += lp[sp * NN + i];
    rinv[i] = 1.0f / s;
}

// ---------------- K3: combine splits from tile layout, normalize, store ------------
__global__ __launch_bounds__(256) void k3_comb(
    const float* __restrict__ accp, const float* __restrict__ rinv, float* __restrict__ out)
{
    int idx = blockIdx.x * 256 + threadIdx.x;   // float4 index over tile storage
    int tile = idx >> 6, l = idx & 63;
    float4 s = make_float4(0.f, 0.f, 0.f, 0.f);
#pragma unroll
    for (int sp = 0; sp < SPLITS; sp++) {
        float4 v = *(const float4*)(accp + (size_t)sp * (NN * FOUT) + (size_t)idx * 4);
        s.x += v.x; s.y += v.y; s.z += v.z; s.w += v.w;
    }
    int row0 = (tile >> 3) * 16 + (l >> 4) * 4;
    int col  = (tile & 7) * 16 + (l & 15);
    float4 ri = *(const float4*)(rinv + row0);
    out[(size_t)(row0 + 0) * FOUT + col] = s.x * ri.x;
    out[(size_t)(row0 + 1) * FOUT + col] = s.y * ri.y;
    out[(size_t)(row0 + 2) * FOUT + col] = s.z * ri.z;
    out[(size_t)(row0 + 3) * FOUT + col] = s.w * ri.w;
}

extern "C" void kernel_launch(void* const* d_in, const int* in_sizes, int n_in,
                              void* d_out, int out_size, void* d_ws, size_t ws_size,
                              hipStream_t stream) {
    const float* h   = (const float*)d_in[0];
    const int*   adj = (const int*)d_in[1];
    const float* W   = (const float*)d_in[2];
    const float* a   = (const float*)d_in[3];
    float* out = (float*)d_out;

    char* ws = (char*)d_ws;
    u16*   whfrag = (u16*)ws;                           // 2 MB
    float* src    = (float*)(ws + (2u << 20));          // 32 KB
    float* dl2e   = src + NN;                           // 32 KB
    u32*   gmaxk  = (u32*)(dl2e + NN);                  // 4 B
    float* accp   = (float*)(ws + (3u << 20));          // 32 MB
    float* lp     = (float*)(ws + (35u << 20));         // 256 KB
    float* rinv   = (float*)(ws + (36u << 20));         // 32 KB

    (void)hipMemsetAsync(gmaxk, 0, sizeof(u32), stream);
    k1_wh<<<dim3(NN / 32), dim3(512), 0, stream>>>(h, W, a, whfrag, src, dl2e, gmaxk);
    k2_attn<<<dim3(NN / 128, SPLITS), dim3(512), 0, stream>>>(adj, src, dl2e, whfrag, gmaxk, accp, lp);
    k2b_rsum<<<dim3(NN / 256), dim3(256), 0, stream>>>(lp, rinv);
    k3_comb<<<dim3((NN * FOUT / 4) / 256), dim3(256), 0, stream>>>(accp, rinv, out);
}

// Round 3
// 421.149 us; speedup vs baseline: 1.1614x; 1.0287x over previous
//
#include <hip/hip_runtime.h>
#include <hip/hip_bf16.h>

typedef unsigned short u16;
typedef unsigned int u32;
typedef __attribute__((ext_vector_type(8))) short short8;
typedef __attribute__((ext_vector_type(4))) float f32x4;

#define NN 8192
#define KIN 256
#define FOUT 128
#define SPLITS 8
#define KPER (NN / SPLITS)   // 1024
#define KSTEPS (KPER / 32)   // 32 k-steps of 32 per split
#define L2E 1.4426950408889634f

__device__ __forceinline__ float exp2fast(float x) { return __builtin_amdgcn_exp2f(x); }

__device__ __forceinline__ u16 f2bf(float f) {
    u32 u = __float_as_uint(f);
    u32 r = ((u >> 16) & 1u) + 0x7fffu;
    return (u16)((u + r) >> 16);
}
__device__ __forceinline__ u32 pk_bf16(float a, float b) {
    union { __hip_bfloat162 h2; u32 u; } cv;
    cv.h2 = __float22bfloat162_rn(make_float2(a, b));   // v_cvt_pk_bf16_f32
    return cv.u;
}
__device__ __forceinline__ u32 fkey(float f) {
    u32 b = __float_as_uint(f);
    return (b & 0x80000000u) ? ~b : (b | 0x80000000u);
}
__device__ __forceinline__ float funkey(u32 k) {
    u32 b = (k & 0x80000000u) ? (k & 0x7fffffffu) : ~k;
    return __uint_as_float(b);
}

// ---------------- K1: Wh = h@W (fp32 acc) -> whfrag (B-fragment-major bf16), src, dst*log2e, gmax
// 512 threads/block (2 waves/SIMD instead of 1 -> W-load latency shared across waves).
// whfrag layout: [(kstep*8 + ntile)*64 + lane] * 8 u16, element j = Wh[kstep*32 + (lane>>4)*8 + j][ntile*16 + (lane&15)]
__global__ __launch_bounds__(512) void k1_wh(
    const float* __restrict__ h, const float* __restrict__ W, const float* __restrict__ a,
    u16* __restrict__ whfrag,
    float* __restrict__ src, float* __restrict__ dl2e, u32* __restrict__ gmaxk)
{
    __shared__ float hT[64][36];
    __shared__ u16   lt[128][40];    // [feature][node] bf16 tile, 80B row stride
    __shared__ float sd[32][2];
    const int t  = threadIdx.x;       // 0..511
    const int m0 = blockIdx.x * 32;   // node block; kstep = blockIdx.x
    const int rq = t >> 5, cq = t & 31;   // rq 0..15, rows rq*2+{0,1}; cols cq*4..+3

    float acc[2][4];
#pragma unroll
    for (int i = 0; i < 2; i++)
#pragma unroll
        for (int j = 0; j < 4; j++) acc[i][j] = 0.f;
    if (t < 64) sd[t >> 1][t & 1] = 0.f;

    for (int kt = 0; kt < KIN; kt += 64) {
        __syncthreads();
        {   // 512 threads stage the full 32x64 h-tile (transposed) in one step
            int r = t >> 4, kc = (t & 15) * 4;
            float4 hv = *(const float4*)(h + (size_t)(m0 + r) * KIN + kt + kc);
            hT[kc + 0][r] = hv.x; hT[kc + 1][r] = hv.y;
            hT[kc + 2][r] = hv.z; hT[kc + 3][r] = hv.w;
        }
        __syncthreads();
        for (int k = 0; k < 64; k++) {
            float4 wv = *(const float4*)(W + (size_t)(kt + k) * FOUT + cq * 4);
            float h0 = hT[k][rq * 2 + 0], h1 = hT[k][rq * 2 + 1];
            acc[0][0] += h0 * wv.x; acc[0][1] += h0 * wv.y; acc[0][2] += h0 * wv.z; acc[0][3] += h0 * wv.w;
            acc[1][0] += h1 * wv.x; acc[1][1] += h1 * wv.y; acc[1][2] += h1 * wv.z; acc[1][3] += h1 * wv.w;
        }
    }
#pragma unroll
    for (int i = 0; i < 2; i++) {
        int row = rq * 2 + i;
        float sp = 0.f, dp = 0.f;
#pragma unroll
        for (int j = 0; j < 4; j++) {
            sp += acc[i][j] * a[cq * 4 + j];
            dp += acc[i][j] * a[FOUT + cq * 4 + j];
            lt[cq * 4 + j][row] = f2bf(acc[i][j]);
        }
        atomicAdd(&sd[row][0], sp);
        atomicAdd(&sd[row][1], dp);
    }
    __syncthreads();
    if (t < 32) { src[m0 + t] = sd[t][0]; dl2e[m0 + t] = sd[t][1] * L2E; }
    if (t < 64) {
        float v = (t < 32) ? sd[t][1] : -3.0e38f;
#pragma unroll
        for (int off = 32; off >= 1; off >>= 1) v = fmaxf(v, __shfl_down(v, off));
        if (t == 0) atomicMax(gmaxk, fkey(v));
    }
    // fragment-major write: 8 ntiles x 64 lanes x 16B, fully coalesced, one step
    const int kstep = blockIdx.x;
    {
        int nt = t >> 6;             // 0..7
        int l  = t & 63;
        short8 v = *(const short8*)&lt[nt * 16 + (l & 15)][(l >> 4) * 8];
        *(short8*)(whfrag + ((size_t)(kstep * 8 + nt) * 64 + l) * 8) = v;
    }
}

// ---------------- K2: barrier-free flash attention; wave = 32-row strip, no LDS -----
// Fat waves: each wave owns TWO 16-row A-fragments and reuses the 8 bv tiles for
// both -> per-row B-fragment traffic/issue halves vs the 16-row version. VALU per
// iter doubles (~400cy), so 2 waves/SIMD retains full latency coverage; depth-2
// adj prefetch slack doubles to ~800cy (~ HBM latency).
__global__ __launch_bounds__(256, 2) void k2_attn(
    const int* __restrict__ adj, const float* __restrict__ src, const float* __restrict__ dl2e,
    const u16* __restrict__ whfrag, const u32* __restrict__ gmaxk,
    float* __restrict__ accp, float* __restrict__ lp)
{
    const int t = threadIdx.x;
    const int lane = t & 63, wave = t >> 6;
    const int strip2 = blockIdx.x * 4 + wave;    // 0..255 (32-row m-tile), grid.x = 64
    const int i0 = strip2 * 32;
    const int split = blockIdx.y;
    const int l15 = lane & 15;
    const int kq = (lane >> 4) * 8;              // this lane's k offset within a 32-step

    float sp0 = src[i0 + l15] * L2E;
    float sp1 = src[i0 + 16 + l15] * L2E;
    float gm = funkey(*gmaxk) * L2E;
    float x0 = sp0 + gm, x1 = sp1 + gm;
    float C0 = fmaxf(x0, 0.01f * x0), C1 = fmaxf(x1, 0.01f * x1);
    const float y1a = sp0 - C0, y2a = 0.01f * sp0 - C0;
    const float y1b = sp1 - C1, y2b = 0.01f * sp1 - C1;

    const int* arow0 = adj + (size_t)(i0 + l15) * NN;        // lane's adj rows
    const int* arow1 = adj + (size_t)(i0 + 16 + l15) * NN;
    const int st0 = blockIdx.x & (KSTEPS - 1);               // stagger windows across blocks
    const int kbase = split * KPER;

    f32x4 acc0[8], acc1[8];
#pragma unroll
    for (int nt = 0; nt < 8; nt++) { acc0[nt] = {0.f, 0.f, 0.f, 0.f}; acc1[nt] = {0.f, 0.f, 0.f, 0.f}; }
    float psum0 = 0.f, psum1 = 0.f;

    // depth-2 register prefetch of adj (no barriers anywhere -> loads stay in flight)
    int4 a0L[2], a0H[2], a1L[2], a1H[2];
#pragma unroll
    for (int s = 0; s < 2; s++) {
        int kb = kbase + ((st0 + s) & (KSTEPS - 1)) * 32;
        a0L[s] = *(const int4*)(arow0 + kb + kq);
        a0H[s] = *(const int4*)(arow0 + kb + kq + 4);
        a1L[s] = *(const int4*)(arow1 + kb + kq);
        a1H[s] = *(const int4*)(arow1 + kb + kq + 4);
    }

#pragma unroll 4
    for (int it = 0; it < KSTEPS; ++it) {
        const int sl = it & 1;
        const int kb = kbase + ((st0 + it) & (KSTEPS - 1)) * 32;

        // B fragments: contiguous 1KB/wave per tile, reused by BOTH row-groups
        uint4 bv[8];
        const u16* wf = whfrag + ((size_t)(kb >> 5) * 8 * 64 + lane) * 8;
#pragma unroll
        for (int nt = 0; nt < 8; nt++)
            bv[nt] = *(const uint4*)(wf + (size_t)nt * 64 * 8);

        // dst values: broadcast loads, L1-resident (shared by both row-groups)
        const float4 dl = *(const float4*)(dl2e + kb + kq);
        const float4 dh = *(const float4*)(dl2e + kb + kq + 4);

        // P for row-group 0 (rows i0..i0+15)
        int4 al = a0L[sl], ah = a0H[sl];
        float q0, q1, q2, q3, q4, q5, q6, q7;
        {
            float x;
            x = fmaxf(y1a + dl.x, y2a + 0.01f * dl.x); q0 = exp2fast(al.x > 0 ? x : -1.0e9f);
            x = fmaxf(y1a + dl.y, y2a + 0.01f * dl.y); q1 = exp2fast(al.y > 0 ? x : -1.0e9f);
            x = fmaxf(y1a + dl.z, y2a + 0.01f * dl.z); q2 = exp2fast(al.z > 0 ? x : -1.0e9f);
            x = fmaxf(y1a + dl.w, y2a + 0.01f * dl.w); q3 = exp2fast(al.w > 0 ? x : -1.0e9f);
            x = fmaxf(y1a + dh.x, y2a + 0.01f * dh.x); q4 = exp2fast(ah.x > 0 ? x : -1.0e9f);
            x = fmaxf(y1a + dh.y, y2a + 0.01f * dh.y); q5 = exp2fast(ah.y > 0 ? x : -1.0e9f);
            x = fmaxf(y1a + dh.z, y2a + 0.01f * dh.z); q6 = exp2fast(ah.z > 0 ? x : -1.0e9f);
            x = fmaxf(y1a + dh.w, y2a + 0.01f * dh.w); q7 = exp2fast(ah.w > 0 ? x : -1.0e9f);
        }
        psum0 += ((q0 + q1) + (q2 + q3)) + ((q4 + q5) + (q6 + q7));
        union { short8 s8; u32 u[4]; } af0;
        af0.u[0] = pk_bf16(q0, q1); af0.u[1] = pk_bf16(q2, q3);
        af0.u[2] = pk_bf16(q4, q5); af0.u[3] = pk_bf16(q6, q7);

        // P for row-group 1 (rows i0+16..i0+31)
        al = a1L[sl]; ah = a1H[sl];
        {
            float x;
            x = fmaxf(y1b + dl.x, y2b + 0.01f * dl.x); q0 = exp2fast(al.x > 0 ? x : -1.0e9f);
            x = fmaxf(y1b + dl.y, y2b + 0.01f * dl.y); q1 = exp2fast(al.y > 0 ? x : -1.0e9f);
            x = fmaxf(y1b + dl.z, y2b + 0.01f * dl.z); q2 = exp2fast(al.z > 0 ? x : -1.0e9f);
            x = fmaxf(y1b + dl.w, y2b + 0.01f * dl.w); q3 = exp2fast(al.w > 0 ? x : -1.0e9f);
            x = fmaxf(y1b + dh.x, y2b + 0.01f * dh.x); q4 = exp2fast(ah.x > 0 ? x : -1.0e9f);
            x = fmaxf(y1b + dh.y, y2b + 0.01f * dh.y); q5 = exp2fast(ah.y > 0 ? x : -1.0e9f);
            x = fmaxf(y1b + dh.z, y2b + 0.01f * dh.z); q6 = exp2fast(ah.z > 0 ? x : -1.0e9f);
            x = fmaxf(y1b + dh.w, y2b + 0.01f * dh.w); q7 = exp2fast(ah.w > 0 ? x : -1.0e9f);
        }
        psum1 += ((q0 + q1) + (q2 + q3)) + ((q4 + q5) + (q6 + q7));
        union { short8 s8; u32 u[4]; } af1;
        af1.u[0] = pk_bf16(q0, q1); af1.u[1] = pk_bf16(q2, q3);
        af1.u[2] = pk_bf16(q4, q5); af1.u[3] = pk_bf16(q6, q7);

        // prefetch it+2 into this slot (wrapped index: always valid, branchless)
        {
            int kb2 = kbase + ((st0 + it + 2) & (KSTEPS - 1)) * 32;
            a0L[sl] = *(const int4*)(arow0 + kb2 + kq);
            a0H[sl] = *(const int4*)(arow0 + kb2 + kq + 4);
            a1L[sl] = *(const int4*)(arow1 + kb2 + kq);
            a1H[sl] = *(const int4*)(arow1 + kb2 + kq + 4);
        }

#pragma unroll
        for (int nt = 0; nt < 8; nt++) {
            union { uint4 q; short8 s8; } bf; bf.q = bv[nt];
            acc0[nt] = __builtin_amdgcn_mfma_f32_16x16x32_bf16(af0.s8, bf.s8, acc0[nt], 0, 0, 0);
            acc1[nt] = __builtin_amdgcn_mfma_f32_16x16x32_bf16(af1.s8, bf.s8, acc1[nt], 0, 0, 0);
        }
    }

    // row sums: reduce over the 4 quads holding each row
    float v0 = psum0;
    v0 += __shfl_down(v0, 32);
    v0 += __shfl_down(v0, 16);
    float v1 = psum1;
    v1 += __shfl_down(v1, 32);
    v1 += __shfl_down(v1, 16);
    if (lane < 16) {
        lp[split * NN + i0 + lane] = v0;
        lp[split * NN + i0 + 16 + lane] = v1;
    }

    // accumulator partials, lane-major tile layout (fully coalesced)
    float* ab2 = accp + (size_t)split * (NN * FOUT);
    const int s16a = strip2 * 2, s16b = strip2 * 2 + 1;
#pragma unroll
    for (int nt = 0; nt < 8; nt++)
        *(f32x4*)&ab2[((size_t)(s16a * 8 + nt) * 64 + lane) * 4] = acc0[nt];
#pragma unroll
    for (int nt = 0; nt < 8; nt++)
        *(f32x4*)&ab2[((size_t)(s16b * 8 + nt) * 64 + lane) * 4] = acc1[nt];
}

// ---------------- K2b: inverse row sums --------------------------------------------
__global__ __launch_bounds__(256) void k2b_rsum(const float* __restrict__ lp,
                                               float* __restrict__ rinv)
{
    int i = blockIdx.x * 256 + threadIdx.x;
    float s = 0.f;
#pragma unroll
    for (int sp = 0; sp < SPLITS; sp++) s += lp[sp * NN + i];
    rinv[i] = 1.0f / s;
}

// ---------------- K3: combine splits from tile layout, normalize, store ------------
__global__ __launch_bounds__(256) void k3_comb(
    const float* __restrict__ accp, const float* __restrict__ rinv, float* __restrict__ out)
{
    int idx = blockIdx.x * 256 + threadIdx.x;   // float4 index over tile storage
    int tile = idx >> 6, l = idx & 63;
    float4 s = make_float4(0.f, 0.f, 0.f, 0.f);
#pragma unroll
    for (int sp = 0; sp < SPLITS; sp++) {
        float4 v = *(const float4*)(accp + (size_t)sp * (NN * FOUT) + (size_t)idx * 4);
        s.x += v.x; s.y += v.y; s.z += v.z; s.w += v.w;
    }
    int row0 = (tile >> 3) * 16 + (l >> 4) * 4;
    int col  = (tile & 7) * 16 + (l & 15);
    float4 ri = *(const float4*)(rinv + row0);
    out[(size_t)(row0 + 0) * FOUT + col] = s.x * ri.x;
    out[(size_t)(row0 + 1) * FOUT + col] = s.y * ri.y;
    out[(size_t)(row0 + 2) * FOUT + col] = s.z * ri.z;
    out[(size_t)(row0 + 3) * FOUT + col] = s.w * ri.w;
}

extern "C" void kernel_launch(void* const* d_in, const int* in_sizes, int n_in,
                              void* d_out, int out_size, void* d_ws, size_t ws_size,
                              hipStream_t stream) {
    const float* h   = (const float*)d_in[0];
    const int*   adj = (const int*)d_in[1];
    const float* W   = (const float*)d_in[2];
    const float* a   = (const float*)d_in[3];
    float* out = (float*)d_out;

    char* ws = (char*)d_ws;
    u16*   whfrag = (u16*)ws;                           // 2 MB
    float* src    = (float*)(ws + (2u << 20));          // 32 KB
    float* dl2e   = src + NN;                           // 32 KB
    u32*   gmaxk  = (u32*)(dl2e + NN);                  // 4 B
    float* accp   = (float*)(ws + (3u << 20));          // 32 MB
    float* lp     = (float*)(ws + (35u << 20));         // 256 KB
    float* rinv   = (float*)(ws + (36u << 20));         // 32 KB

    (void)hipMemsetAsync(gmaxk, 0, sizeof(u32), stream);
    k1_wh<<<dim3(NN / 32), dim3(512), 0, stream>>>(h, W, a, whfrag, src, dl2e, gmaxk);
    k2_attn<<<dim3(NN / 128, SPLITS), dim3(256), 0, stream>>>(adj, src, dl2e, whfrag, gmaxk, accp, lp);
    k2b_rsum<<<dim3(NN / 256), dim3(256), 0, stream>>>(lp, rinv);
    k3_comb<<<dim3((NN * FOUT / 4) / 256), dim3(256), 0, stream>>>(accp, rinv, out);
}